// Round 15
// baseline (123.177 us; speedup 1.0000x reference)
//
#include <hip/hip_runtime.h>
#include <hip/hip_bf16.h>
#include <math.h>

#define BATCH 2
#define SEQ 196
#define DMODEL 768
#define NHEAD 12
#define DHEAD 64
#define DFF 3072
#define NROWS (BATCH*SEQ)        // 392
#define NBH   (BATCH*NHEAD)     // 24
#define NHROWS (NBH*SEQ)        // 4704

typedef __attribute__((ext_vector_type(8))) short short8;
typedef __attribute__((ext_vector_type(4))) float f32x4;

// ---------- utilities ----------
__device__ __forceinline__ short f2bf(float f) {
  unsigned u = __builtin_bit_cast(unsigned, f);
  u += 0x7FFFu + ((u >> 16) & 1u);      // round-to-nearest-even
  return (short)(u >> 16);
}
__device__ __forceinline__ float bf2f(short s) {
  unsigned u = ((unsigned)(unsigned short)s) << 16;
  return __builtin_bit_cast(float, u);
}
__device__ __forceinline__ float wave_sum64(float v) {
  #pragma unroll
  for (int off = 32; off; off >>= 1) v += __shfl_xor(v, off);
  return v;
}

__device__ __forceinline__ void block_reduce_sum4(float& a, float& b, float& c, float& d,
                                                  float* sbuf /*>=16 floats*/) {
  #pragma unroll
  for (int off = 32; off; off >>= 1) {
    a += __shfl_xor(a, off);
    b += __shfl_xor(b, off);
    c += __shfl_xor(c, off);
    d += __shfl_xor(d, off);
  }
  int wid = threadIdx.x >> 6;
  if ((threadIdx.x & 63) == 0) {
    sbuf[wid*4+0] = a; sbuf[wid*4+1] = b; sbuf[wid*4+2] = c; sbuf[wid*4+3] = d;
  }
  __syncthreads();
  a = sbuf[0] + sbuf[4] + sbuf[8]  + sbuf[12];
  b = sbuf[1] + sbuf[5] + sbuf[9]  + sbuf[13];
  c = sbuf[2] + sbuf[6] + sbuf[10] + sbuf[14];
  d = sbuf[3] + sbuf[7] + sbuf[11] + sbuf[15];
  __syncthreads();
}

#define PITCH 72     // 64-wide K-step LDS pitch
#define PITCH2 136   // 128-wide K-step LDS pitch

// ---------- QKV GEMM: f32 in, inline bf16 cvt, split-K=2; z = mat*2 + slice ----------
__global__ __launch_bounds__(256) void gemm_qkv_f32(
    const float* __restrict__ X,
    const float* __restrict__ Wq, const float* __restrict__ Wk, const float* __restrict__ Wv,
    float* __restrict__ parts) {
  const int z = blockIdx.z, mat = z >> 1, slice = z & 1;
  const float* W = (mat == 0) ? Wq : (mat == 1) ? Wk : Wv;
  float* Y = parts + (size_t)z * NROWS * DMODEL;
  const int K = DMODEL, m = DMODEL, n = NROWS;
  const int kbase = slice * (DMODEL/2);

  __shared__ short As[64*PITCH];
  __shared__ short Bs[64*PITCH];
  const int tid  = threadIdx.x;
  const int lane = tid & 63;
  const int w    = tid >> 6, wr = w >> 1, wc = w & 1;
  const int brow = blockIdx.y * 64, bcol = blockIdx.x * 64;

  const int sr = tid >> 2, sc = (tid & 3) * 16;
  const bool rok = (brow + sr) < n;
  const float* xp = X + (size_t)(brow + sr) * K + kbase + sc;
  const float* wp = W + (size_t)(bcol + sr) * K + kbase + sc;

  f32x4 acc[2][2] = {};
  const int kgo = (lane >> 4) * 8;
  const f32x4 zf = {0.f,0.f,0.f,0.f};

  f32x4 xa[4], wa[4];
  #pragma unroll
  for (int q = 0; q < 4; ++q) {
    xa[q] = rok ? *(const f32x4*)(xp + q*4) : zf;
    wa[q] = *(const f32x4*)(wp + q*4);
  }

  const int T = (DMODEL/2) / 64;   // 6
  for (int t = 0; t < T; ++t) {
    f32x4 xn[4], wn[4];
    const int kn = (t + 1 < T) ? (t + 1) * 64 : 0;
    #pragma unroll
    for (int q = 0; q < 4; ++q) {
      xn[q] = rok ? *(const f32x4*)(xp + kn + q*4) : zf;
      wn[q] = *(const f32x4*)(wp + kn + q*4);
    }

    short8 xs0, xs1, ws0, ws1;
    #pragma unroll
    for (int j = 0; j < 4; ++j) {
      xs0[j] = f2bf(xa[0][j]); xs0[j+4] = f2bf(xa[1][j]);
      xs1[j] = f2bf(xa[2][j]); xs1[j+4] = f2bf(xa[3][j]);
      ws0[j] = f2bf(wa[0][j]); ws0[j+4] = f2bf(wa[1][j]);
      ws1[j] = f2bf(wa[2][j]); ws1[j+4] = f2bf(wa[3][j]);
    }
    __syncthreads();
    *(short8*)&As[sr*PITCH + sc]     = xs0;
    *(short8*)&As[sr*PITCH + sc + 8] = xs1;
    *(short8*)&Bs[sr*PITCH + sc]     = ws0;
    *(short8*)&Bs[sr*PITCH + sc + 8] = ws1;
    __syncthreads();

    #pragma unroll
    for (int kk = 0; kk < 2; ++kk) {
      short8 a0 = *(const short8*)&As[(wr*32      + (lane & 15))*PITCH + kk*32 + kgo];
      short8 a1 = *(const short8*)&As[(wr*32 + 16 + (lane & 15))*PITCH + kk*32 + kgo];
      short8 b0 = *(const short8*)&Bs[(wc*32      + (lane & 15))*PITCH + kk*32 + kgo];
      short8 b1 = *(const short8*)&Bs[(wc*32 + 16 + (lane & 15))*PITCH + kk*32 + kgo];
      acc[0][0] = __builtin_amdgcn_mfma_f32_16x16x32_bf16(a0, b0, acc[0][0], 0, 0, 0);
      acc[0][1] = __builtin_amdgcn_mfma_f32_16x16x32_bf16(a0, b1, acc[0][1], 0, 0, 0);
      acc[1][0] = __builtin_amdgcn_mfma_f32_16x16x32_bf16(a1, b0, acc[1][0], 0, 0, 0);
      acc[1][1] = __builtin_amdgcn_mfma_f32_16x16x32_bf16(a1, b1, acc[1][1], 0, 0, 0);
    }
    #pragma unroll
    for (int q = 0; q < 4; ++q) { xa[q] = xn[q]; wa[q] = wn[q]; }
  }

  const int ccol = bcol + wc*32 + (lane & 15);
  #pragma unroll
  for (int mr = 0; mr < 2; ++mr) {
    #pragma unroll
    for (int j = 0; j < 4; ++j) {
      int grow = brow + wr*32 + mr*16 + (lane >> 4)*4 + j;
      if (grow < n) {
        float* yr = Y + (size_t)grow * m + ccol;
        yr[0]  = acc[mr][0][j];
        yr[16] = acc[mr][1][j];
      }
    }
  }
}

// ---------- GEMM: A bf16, W f32 (inline cvt), split-K via z, K_STEP=128 ----------
__global__ __launch_bounds__(256) void gemm_awf32(
    const short* __restrict__ A, const float* __restrict__ W,
    float* __restrict__ Yparts, int n, int Ktot, int m, int KK) {
  const int z = blockIdx.z;
  const int kbase = z * KK;
  float* Y = Yparts + (size_t)z * n * m;

  __shared__ short As[64*PITCH2];
  __shared__ short Bs[64*PITCH2];
  const int tid  = threadIdx.x;
  const int lane = tid & 63;
  const int w    = tid >> 6, wr = w >> 1, wc = w & 1;
  const int brow = blockIdx.y * 64, bcol = blockIdx.x * 64;

  const int sr = tid >> 2, sc = (tid & 3) * 32;
  const bool rok = (brow + sr) < n;
  const short* ap = A + (size_t)(brow + sr) * Ktot + kbase + sc;
  const float* wp = W + (size_t)(bcol + sr) * Ktot + kbase + sc;

  f32x4 acc[2][2] = {};
  const int kgo = (lane >> 4) * 8;
  const short8 z8 = {0,0,0,0,0,0,0,0};

  short8 aa[4];
  f32x4 wa[8];
  #pragma unroll
  for (int q = 0; q < 4; ++q) aa[q] = rok ? *(const short8*)(ap + q*8) : z8;
  #pragma unroll
  for (int q = 0; q < 8; ++q) wa[q] = *(const f32x4*)(wp + q*4);

  const int T = KK / 128;
  for (int t = 0; t < T; ++t) {
    short8 an[4];
    f32x4 wn[8];
    const int kn = (t + 1 < T) ? (t + 1) * 128 : 0;
    #pragma unroll
    for (int q = 0; q < 4; ++q) an[q] = rok ? *(const short8*)(ap + kn + q*8) : z8;
    #pragma unroll
    for (int q = 0; q < 8; ++q) wn[q] = *(const f32x4*)(wp + kn + q*4);

    short8 ws[4];
    #pragma unroll
    for (int s = 0; s < 4; ++s) {
      #pragma unroll
      for (int j = 0; j < 4; ++j) {
        ws[s][j]   = f2bf(wa[2*s][j]);
        ws[s][j+4] = f2bf(wa[2*s+1][j]);
      }
    }
    __syncthreads();
    #pragma unroll
    for (int s = 0; s < 4; ++s) {
      *(short8*)&As[sr*PITCH2 + sc + s*8] = aa[s];
      *(short8*)&Bs[sr*PITCH2 + sc + s*8] = ws[s];
    }
    __syncthreads();

    #pragma unroll
    for (int kk = 0; kk < 4; ++kk) {
      short8 a0 = *(const short8*)&As[(wr*32      + (lane & 15))*PITCH2 + kk*32 + kgo];
      short8 a1 = *(const short8*)&As[(wr*32 + 16 + (lane & 15))*PITCH2 + kk*32 + kgo];
      short8 b0 = *(const short8*)&Bs[(wc*32      + (lane & 15))*PITCH2 + kk*32 + kgo];
      short8 b1 = *(const short8*)&Bs[(wc*32 + 16 + (lane & 15))*PITCH2 + kk*32 + kgo];
      acc[0][0] = __builtin_amdgcn_mfma_f32_16x16x32_bf16(a0, b0, acc[0][0], 0, 0, 0);
      acc[0][1] = __builtin_amdgcn_mfma_f32_16x16x32_bf16(a0, b1, acc[0][1], 0, 0, 0);
      acc[1][0] = __builtin_amdgcn_mfma_f32_16x16x32_bf16(a1, b0, acc[1][0], 0, 0, 0);
      acc[1][1] = __builtin_amdgcn_mfma_f32_16x16x32_bf16(a1, b1, acc[1][1], 0, 0, 0);
    }
    #pragma unroll
    for (int q = 0; q < 4; ++q) aa[q] = an[q];
    #pragma unroll
    for (int q = 0; q < 8; ++q) wa[q] = wn[q];
  }

  const int ccol = bcol + wc*32 + (lane & 15);
  #pragma unroll
  for (int mr = 0; mr < 2; ++mr) {
    #pragma unroll
    for (int j = 0; j < 4; ++j) {
      int grow = brow + wr*32 + mr*16 + (lane >> 4)*4 + j;
      if (grow < n) {
        float* yr = Y + (size_t)grow * m + ccol;
        yr[0]  = acc[mr][0][j];
        yr[16] = acc[mr][1][j];
      }
    }
  }
}

// ---------- fused QKV post (sums 2 split-K partials) ----------
#define P_P 256
__global__ __launch_bounds__(256) void qkv_post(const float* __restrict__ X,
                                                const float* __restrict__ parts,
                                                const float* __restrict__ bq,
                                                const float* __restrict__ bk,
                                                const float* __restrict__ bv,
                                                short* __restrict__ qhb,
                                                short* __restrict__ khb,
                                                float* __restrict__ q2s,
                                                float* __restrict__ k2s,
                                                short* __restrict__ lvT) {
  __shared__ float sbuf[16];
  const int r = blockIdx.x;
  const int b = r / SEQ, s = r % SEQ;
  const int y = blockIdx.y;
  const float* p0 = parts + (size_t)(2*y)   * NROWS * DMODEL + (size_t)r*DMODEL;
  const float* p1 = parts + (size_t)(2*y+1) * NROWS * DMODEL + (size_t)r*DMODEL;
  const float* bias = (y == 0) ? bq : (y == 1) ? bk : bv;
  const float* xr = X + (size_t)r*DMODEL;
  const int tid = threadIdx.x, wid = tid >> 6, lane = tid & 63;
  const float maxn = 1.0f - 1e-5f;

  float xs = 0.f, ms = 0.f, mb = 0.f, bb = 0.f;
  float mv[3], bvv[3];
  #pragma unroll
  for (int l = 0; l < 3; ++l) {
    int i = tid + l*256;
    float xv = xr[i];
    mv[l] = p0[i] + p1[i]; bvv[l] = bias[i];
    xs += xv*xv; ms += mv[l]*mv[l]; mb += mv[l]*bvv[l]; bb += bvv[l]*bvv[l];
  }
  block_reduce_sum4(xs, ms, mb, bb, sbuf);
  float xn  = sqrtf(fmaxf(xs, 1e-15f));
  float mxn = sqrtf(fmaxf(ms, 1e-15f));
  float art = atanhf(fminf(xn, maxn));
  float scm = tanhf(mxn/xn*art)/mxn;
  float x2 = scm*scm*ms;
  float y2 = bb;
  float xy = scm*mb;
  float den = fmaxf(1.f + 2.f*xy + x2*y2, 1e-15f);
  float ca = (1.f + 2.f*xy + y2) * scm / den;
  float cb = (1.f - x2) / den;

  #pragma unroll
  for (int l = 0; l < 3; ++l) {
    float o = ca*mv[l] + cb*bvv[l];
    int h = l*4 + wid;
    size_t hr = (size_t)(b*NHEAD + h)*SEQ + s;
    if (y < 2) {
      short c16 = f2bf(fminf(o, maxn));
      float cf = bf2f(c16);
      float nn = wave_sum64(cf*cf);
      if (y == 0) {
        qhb[hr*64 + lane] = c16;
        if (lane == 0) q2s[hr] = nn;
      } else {
        khb[hr*64 + lane] = c16;
        if (lane == 0) k2s[hr] = nn;
      }
    } else {
      float nn = wave_sum64(o*o);
      float n = sqrtf(fmaxf(nn, 1e-15f));
      float scl = atanhf(fminf(n, maxn))/n;
      lvT[((size_t)(b*NHEAD + h)*DHEAD + lane)*P_P + s] = f2bf(scl*o);
    }
  }
}

// ---------- fully fused attention (round-9-verified) ----------
#define SP 72
#define PP 264
__global__ __launch_bounds__(256) void attn_mfma(
    const short* __restrict__ qhb, const short* __restrict__ khb,
    const float* __restrict__ q2s, const float* __restrict__ k2s,
    const short* __restrict__ lvT, const float* __restrict__ hs,
    short* __restrict__ aob) {
  __shared__ __align__(16) char smem[9216 + 224*SP*2];
  __shared__ float q2l[64];
  __shared__ float k2l[224];
  __shared__ float redA[64][2];
  __shared__ float redB[64][2];

  const int tile = blockIdx.x, bh = blockIdx.z;
  const int h = bh % NHEAD, b = bh / NHEAD;
  const int i0 = tile*64;
  const int tid = threadIdx.x, lane = tid & 63, w = tid >> 6, wr = w >> 1, wc = w & 1;
  short* Qs = (short*)smem;
  short* Ks = (short*)(smem + 9216);
  short* Pl = (short*)smem;
  const short8 z8 = {0,0,0,0,0,0,0,0};
  const int kgo = (lane >> 4)*8;

  {
    int row = tid >> 2, seg = (tid & 3)*16;
    int gr = i0 + row;
    short8 v0 = z8, v1 = z8;
    if (gr < SEQ) {
      const short* p = qhb + ((size_t)bh*SEQ + gr)*64 + seg;
      v0 = *(const short8*)p; v1 = *(const short8*)(p + 8);
    }
    *(short8*)&Qs[row*SP + seg]     = v0;
    *(short8*)&Qs[row*SP + seg + 8] = v1;
  }
  for (int u = tid; u < 224*4; u += 256) {
    int row = u >> 2, seg = (u & 3)*16;
    short8 v0 = z8, v1 = z8;
    if (row < SEQ) {
      const short* p = khb + ((size_t)bh*SEQ + row)*64 + seg;
      v0 = *(const short8*)p; v1 = *(const short8*)(p + 8);
    }
    *(short8*)&Ks[row*SP + seg]     = v0;
    *(short8*)&Ks[row*SP + seg + 8] = v1;
  }
  if (tid < 64)  q2l[tid] = (i0 + tid < SEQ) ? q2s[(size_t)bh*SEQ + i0 + tid] : 0.f;
  if (tid < 224) k2l[tid] = (tid < SEQ) ? k2s[(size_t)bh*SEQ + tid] : 0.f;
  __syncthreads();

  f32x4 acc[2][7] = {};
  #pragma unroll
  for (int kk = 0; kk < 2; ++kk) {
    short8 a0 = *(const short8*)&Qs[(wr*32      + (lane & 15))*SP + kk*32 + kgo];
    short8 a1 = *(const short8*)&Qs[(wr*32 + 16 + (lane & 15))*SP + kk*32 + kgo];
    #pragma unroll
    for (int cf = 0; cf < 7; ++cf) {
      short8 bf = *(const short8*)&Ks[(wc*112 + cf*16 + (lane & 15))*SP + kk*32 + kgo];
      acc[0][cf] = __builtin_amdgcn_mfma_f32_16x16x32_bf16(a0, bf, acc[0][cf], 0, 0, 0);
      acc[1][cf] = __builtin_amdgcn_mfma_f32_16x16x32_bf16(a1, bf, acc[1][cf], 0, 0, 0);
    }
  }

  const float inv_hsv = 1.f/(hs[h]*8.0f);
  #pragma unroll
  for (int rf = 0; rf < 2; ++rf) {
    #pragma unroll
    for (int j = 0; j < 4; ++j) {
      int rl = wr*32 + rf*16 + (lane >> 4)*4 + j;
      float q2 = q2l[rl];
      #pragma unroll
      for (int cf = 0; cf < 7; ++cf) {
        int col = wc*112 + cf*16 + (lane & 15);
        float kq = acc[rf][cf][j];
        float k2 = k2l[col];
        float xy = -kq;
        float al = 1.f + 2.f*xy + q2;
        float be = 1.f - k2;
        float num2 = al*al*k2 + 2.f*al*be*xy + be*be*q2;
        float den  = fmaxf(1.f + 2.f*xy + k2*q2, 1e-15f);
        float dns  = num2/(den*den);
        float denom = (1.f - q2)*(1.f - k2) + 1e-15f;
        float arg = fmaxf(1.f + 2.f*dns/denom, 1.f + 1e-7f);
        float dist = logf(arg + sqrtf(arg*arg - 1.f));
        acc[rf][cf][j] = (col < SEQ) ? -dist*inv_hsv : -1e30f;
      }
      float m = acc[rf][0][j];
      #pragma unroll
      for (int cf = 1; cf < 7; ++cf) m = fmaxf(m, acc[rf][cf][j]);
      m = fmaxf(m, __shfl_xor(m, 1));
      m = fmaxf(m, __shfl_xor(m, 2));
      m = fmaxf(m, __shfl_xor(m, 4));
      m = fmaxf(m, __shfl_xor(m, 8));
      if ((lane & 15) == 0) redA[rl][wc] = m;
    }
  }
  __syncthreads();

  #pragma unroll
  for (int rf = 0; rf < 2; ++rf) {
    #pragma unroll
    for (int j = 0; j < 4; ++j) {
      int rl = wr*32 + rf*16 + (lane >> 4)*4 + j;
      float m = fmaxf(redA[rl][0], redA[rl][1]);
      float s = 0.f;
      #pragma unroll
      for (int cf = 0; cf < 7; ++cf) {
        float e = expf(acc[rf][cf][j] - m);
        acc[rf][cf][j] = e;
        s += e;
      }
      s += __shfl_xor(s, 1); s += __shfl_xor(s, 2);
      s += __shfl_xor(s, 4); s += __shfl_xor(s, 8);
      if ((lane & 15) == 0) redB[rl][wc] = s;
    }
  }
  __syncthreads();

  #pragma unroll
  for (int rf = 0; rf < 2; ++rf) {
    #pragma unroll
    for (int j = 0; j < 4; ++j) {
      int rl = wr*32 + rf*16 + (lane >> 4)*4 + j;
      float inv = 1.f/(redB[rl][0] + redB[rl][1]);
      #pragma unroll
      for (int cf = 0; cf < 7; ++cf) {
        int col = wc*112 + cf*16 + (lane & 15);
        Pl[rl*PP + col] = f2bf(acc[rf][cf][j]*inv);
      }
    }
  }
  __syncthreads();

  f32x4 acc2[2][2] = {};
  const short* lvb = lvT + (size_t)bh*DHEAD*P_P;
  #pragma unroll
  for (int ks = 0; ks < 7; ++ks) {
    short8 a0 = *(const short8*)&Pl[(wr*32      + (lane & 15))*PP + ks*32 + kgo];
    short8 a1 = *(const short8*)&Pl[(wr*32 + 16 + (lane & 15))*PP + ks*32 + kgo];
    short8 b0 = *(const short8*)(lvb + (size_t)(wc*32      + (lane & 15))*P_P + ks*32 + kgo);
    short8 b1 = *(const short8*)(lvb + (size_t)(wc*32 + 16 + (lane & 15))*P_P + ks*32 + kgo);
    acc2[0][0] = __builtin_amdgcn_mfma_f32_16x16x32_bf16(a0, b0, acc2[0][0], 0, 0, 0);
    acc2[0][1] = __builtin_amdgcn_mfma_f32_16x16x32_bf16(a0, b1, acc2[0][1], 0, 0, 0);
    acc2[1][0] = __builtin_amdgcn_mfma_f32_16x16x32_bf16(a1, b0, acc2[1][0], 0, 0, 0);
    acc2[1][1] = __builtin_amdgcn_mfma_f32_16x16x32_bf16(a1, b1, acc2[1][1], 0, 0, 0);
  }

  #pragma unroll
  for (int rf = 0; rf < 2; ++rf) {
    #pragma unroll
    for (int j = 0; j < 4; ++j) {
      int rl = wr*32 + rf*16 + (lane >> 4)*4 + j;
      float s = acc2[rf][0][j]*acc2[rf][0][j] + acc2[rf][1][j]*acc2[rf][1][j];
      s += __shfl_xor(s, 1); s += __shfl_xor(s, 2);
      s += __shfl_xor(s, 4); s += __shfl_xor(s, 8);
      if ((lane & 15) == 0) redA[rl][wc] = s;
    }
  }
  __syncthreads();

  #pragma unroll
  for (int rf = 0; rf < 2; ++rf) {
    #pragma unroll
    for (int j = 0; j < 4; ++j) {
      int rl = wr*32 + rf*16 + (lane >> 4)*4 + j;
      int grow = i0 + rl;
      if (grow < SEQ) {
        float n2 = redA[rl][0] + redA[rl][1];
        float n = sqrtf(fmaxf(n2, 1e-15f));
        float scl = tanhf(n)/n;
        #pragma unroll
        for (int cf2 = 0; cf2 < 2; ++cf2) {
          int col = h*64 + wc*32 + cf2*16 + (lane & 15);
          float o = scl*acc2[rf][cf2][j];
          aob[(size_t)(b*SEQ + grow)*DMODEL + col] = f2bf(o);
        }
      }
    }
  }
}

// ---------- fused hyp_linear epilogue + residual + hyp layer norm (split-K partial sum) ----------
__global__ __launch_bounds__(256) void post_resid_ln(
    const short* __restrict__ Xbf, const float* __restrict__ xsArr, int din,
    const float* __restrict__ MXp, int nparts,
    const float* __restrict__ bias, const float* __restrict__ RX,
    const float* __restrict__ betap, const float* __restrict__ lnw,
    const float* __restrict__ lnb,
    float* __restrict__ out, short* __restrict__ outb) {
  __shared__ float sbuf[16];
  const int r = blockIdx.x;
  const int tid = threadIdx.x;

  float xs = 0.f, ms = 0.f, mb = 0.f, bb = 0.f;
  float mv[3], bvv[3];
  #pragma unroll
  for (int l = 0; l < 3; ++l) {
    int i = tid + l*256;
    float acc = 0.f;
    for (int p = 0; p < nparts; ++p)
      acc += MXp[(size_t)p*NROWS*DMODEL + (size_t)r*DMODEL + i];
    mv[l] = acc; bvv[l] = bias[i];
    ms += mv[l]*mv[l]; mb += mv[l]*bvv[l]; bb += bvv[l]*bvv[l];
  }
  if (Xbf) {
    const short* xr = Xbf + (size_t)r*din;
    for (int i = tid; i < din; i += 256) { float v = bf2f(xr[i]); xs += v*v; }
  }
  block_reduce_sum4(xs, ms, mb, bb, sbuf);
  if (!Xbf) xs = xsArr[r];

  float xn  = sqrtf(fmaxf(xs, 1e-15f));
  float mxn = sqrtf(fmaxf(ms, 1e-15f));
  float art = atanhf(fminf(xn, 1.f - 1e-5f));
  float scm = tanhf(mxn/xn*art)/mxn;
  float px2 = scm*scm*ms;
  float py2 = bb;
  float pxy = scm*mb;
  float pden = fmaxf(1.f + 2.f*pxy + px2*py2, 1e-15f);
  float pca = (1.f + 2.f*pxy + py2) * scm / pden;
  float pcb = (1.f - px2) / pden;

  const float* xr2 = RX + (size_t)r*DMODEL;
  float xv[3], yv[3];
  float x2 = 0.f, xy = 0.f, d1 = 0.f, d2 = 0.f;
  #pragma unroll
  for (int l = 0; l < 3; ++l) {
    int i = tid + l*256;
    xv[l] = xr2[i];
    yv[l] = pca*mv[l] + pcb*bvv[l];
    x2 += xv[l]*xv[l]; xy += xv[l]*yv[l];
  }
  block_reduce_sum4(x2, xy, d1, d2, sbuf);
  float yy = pca*pca*ms + 2.f*pca*pcb*mb + pcb*pcb*bb;

  float beta = betap[0];
  float ny = sqrtf(fmaxf(yy, 1e-15f));
  float scs = tanhf(beta * atanhf(fminf(ny, 1.f - 1e-5f))) / ny;
  float y2  = scs*scs*yy;
  float xys = scs*xy;
  float den = fmaxf(1.f + 2.f*xys + x2*y2, 1e-15f);
  float ca = (1.f + 2.f*xys + y2)/den;
  float cb = (1.f - x2)*scs/den;
  float hv[3]; float h2 = 0.f;
  #pragma unroll
  for (int l = 0; l < 3; ++l) { hv[l] = ca*xv[l] + cb*yv[l]; h2 += hv[l]*hv[l]; }
  float z1 = 0.f, z2 = 0.f, z3 = 0.f;
  block_reduce_sum4(h2, z1, z2, z3, sbuf);

  float nh = sqrtf(fmaxf(h2, 1e-15f));
  float scl = atanhf(fminf(nh, 1.f - 1e-5f))/nh;
  float tv[3]; float tsum = 0.f, tsq = 0.f;
  #pragma unroll
  for (int l = 0; l < 3; ++l) { tv[l] = scl*hv[l]; tsum += tv[l]; tsq += tv[l]*tv[l]; }
  float zz = 0.f, zw = 0.f;
  block_reduce_sum4(tsum, tsq, zz, zw, sbuf);
  float mu  = tsum * (1.f/768.f);
  float var = tsq * (1.f/768.f) - mu*mu;
  float rstd = rsqrtf(var + 1e-5f);
  float lnv[3]; float l2 = 0.f;
  #pragma unroll
  for (int l = 0; l < 3; ++l) {
    int i = tid + l*256;
    lnv[l] = (tv[l] - mu)*rstd*lnw[i] + lnb[i];
    l2 += lnv[l]*lnv[l];
  }
  float w1 = 0.f, w2 = 0.f, w3 = 0.f;
  block_reduce_sum4(l2, w1, w2, w3, sbuf);
  float nl = sqrtf(fmaxf(l2, 1e-15f));
  float sce = tanhf(nl)/nl;
  #pragma unroll
  for (int l = 0; l < 3; ++l) {
    int i = tid + l*256;
    float o = sce*lnv[l];
    out[(size_t)r*DMODEL + i] = o;
    if (outb) outb[(size_t)r*DMODEL + i] = f2bf(o);
  }
}

// ---------- fused FFN1 epilogue (sums 2 split-K partials) ----------
__global__ __launch_bounds__(256) void ffn1_post(const float* __restrict__ hb,
                                                 const float* __restrict__ MXp,
                                                 const float* __restrict__ bias,
                                                 short* __restrict__ fbb,
                                                 float* __restrict__ fnorm) {
  __shared__ float sbuf[16];
  const int r = blockIdx.x;
  const int tid = threadIdx.x;
  const float* xr = hb + (size_t)r*DMODEL;
  const float* mr0 = MXp + (size_t)r*DFF;
  const float* mr1 = MXp + (size_t)NROWS*DFF + (size_t)r*DFF;

  float xs = 0.f, ms = 0.f, mb = 0.f, bb = 0.f;
  float mv[12], bvv[12];
  for (int i = tid; i < DMODEL; i += 256) { float v = xr[i]; xs += v*v; }
  #pragma unroll
  for (int l = 0; l < 12; ++l) {
    int i = tid + l*256;
    mv[l] = mr0[i] + mr1[i]; bvv[l] = bias[i];
    ms += mv[l]*mv[l]; mb += mv[l]*bvv[l]; bb += bvv[l]*bvv[l];
  }
  block_reduce_sum4(xs, ms, mb, bb, sbuf);
  float xn  = sqrtf(fmaxf(xs, 1e-15f));
  float mxn = sqrtf(fmaxf(ms, 1e-15f));
  float art = atanhf(fminf(xn, 1.f - 1e-5f));
  float scm = tanhf(mxn/xn*art)/mxn;
  float px2 = scm*scm*ms;
  float py2 = bb;
  float pxy = scm*mb;
  float pden = fmaxf(1.f + 2.f*pxy + px2*py2, 1e-15f);
  float pca = (1.f + 2.f*pxy + py2) * scm / pden;
  float pcb = (1.f - px2) / pden;

  float s2 = pca*pca*ms + 2.f*pca*pcb*mb + pcb*pcb*bb;
  float n = sqrtf(fmaxf(s2, 1e-15f));
  float scl = atanhf(fminf(n, 1.f - 1e-5f))/n;
  float rv[12]; float r2 = 0.f;
  #pragma unroll
  for (int l = 0; l < 12; ++l) {
    float f = pca*mv[l] + pcb*bvv[l];
    rv[l] = fmaxf(scl*f, 0.f);
    r2 += rv[l]*rv[l];
  }
  float w1 = 0.f, w2 = 0.f, w3 = 0.f;
  block_reduce_sum4(r2, w1, w2, w3, sbuf);
  float nr = sqrtf(fmaxf(r2, 1e-15f));
  float sce = tanhf(nr)/nr;
  #pragma unroll
  for (int l = 0; l < 12; ++l)
    fbb[(size_t)r*DFF + tid + l*256] = f2bf(sce*rv[l]);
  if (tid == 0) fnorm[r] = sce*sce*r2;
}

extern "C" void kernel_launch(void* const* d_in, const int* in_sizes, int n_in,
                              void* d_out, int out_size, void* d_ws, size_t ws_size,
                              hipStream_t stream) {
  const float* x    = (const float*)d_in[0];
  const float* wq   = (const float*)d_in[1];
  const float* bq   = (const float*)d_in[2];
  const float* wk   = (const float*)d_in[3];
  const float* bk   = (const float*)d_in[4];
  const float* wv   = (const float*)d_in[5];
  const float* bv   = (const float*)d_in[6];
  const float* wo   = (const float*)d_in[7];
  const float* bo   = (const float*)d_in[8];
  const float* hs   = (const float*)d_in[9];
  const float* w1   = (const float*)d_in[10];
  const float* b1   = (const float*)d_in[11];
  const float* w2   = (const float*)d_in[12];
  const float* b2   = (const float*)d_in[13];
  const float* beta = (const float*)d_in[14];
  const float* ln1w = (const float*)d_in[15];
  const float* ln1b = (const float*)d_in[16];
  const float* ln2w = (const float*)d_in[17];
  const float* ln2b = (const float*)d_in[18];
  float* out = (float*)d_out;

  char* base = (char*)d_ws;
  size_t off = 0;
  auto allocB = [&](size_t bytes) {
    off = (off + 63) & ~(size_t)63;
    void* p = base + off; off += bytes; return p;
  };
  short* aob  = (short*)allocB((size_t)NROWS*DMODEL * 2);
  short* hbb  = (short*)allocB((size_t)NROWS*DMODEL * 2);
  short* fbb  = (short*)allocB((size_t)NROWS*DFF * 2);
  float* qparts = (float*)allocB((size_t)6*NROWS*DMODEL * 4);   // QKV split-K partials
  float* gparts = (float*)allocB((size_t)4*NROWS*DMODEL * 4);   // O / FFN2 partials
  float* tmpF2  = (float*)allocB((size_t)2*NROWS*DFF * 4);      // FFN1 partials
  short* qhb  = (short*)allocB((size_t)NHROWS*DHEAD * 2);
  short* khb  = (short*)allocB((size_t)NHROWS*DHEAD * 2);
  float* q2s  = (float*)allocB((size_t)NHROWS * 4);
  float* k2s  = (float*)allocB((size_t)NHROWS * 4);
  short* lvT  = (short*)allocB((size_t)NBH*DHEAD*P_P * 2);
  float* hb   = (float*)allocB((size_t)NROWS*DMODEL * 4);
  float* fnorm= (float*)allocB((size_t)NROWS * 4);

  dim3 blk(256);
  dim3 gQKV(DMODEL/64, (NROWS+63)/64, 6);   // split-K=2 x 3 mats = 504 blocks
  dim3 gO(DMODEL/64,   (NROWS+63)/64, 2);   // split-K=2, 168 blocks, KK=384
  dim3 gF1(DFF/64,     (NROWS+63)/64, 2);   // split-K=2, 672 blocks, KK=384
  dim3 gF2(DMODEL/64,  (NROWS+63)/64, 4);   // split-K=4, 336 blocks, KK=768
  dim3 gATT(4, 1, NBH);                     // 96 blocks

  // QKV projections (inline f32->bf16, split-K=2) + fused post
  gemm_qkv_f32<<<gQKV, blk, 0, stream>>>(x, wq, wk, wv, qparts);
  qkv_post<<<dim3(NROWS, 3), blk, 0, stream>>>(x, qparts, bq, bk, bv,
                                               qhb, khb, q2s, k2s, lvT);

  // fused attention
  attn_mfma<<<gATT, blk, 0, stream>>>(qhb, khb, q2s, k2s, lvT, hs, aob);

  // output projection (split-K=2) + fused post/residual/LN1
  gemm_awf32<<<gO, blk, 0, stream>>>(aob, wo, gparts, NROWS, DMODEL, DMODEL, DMODEL/2);
  post_resid_ln<<<NROWS, blk, 0, stream>>>(aob, nullptr, DMODEL, gparts, 2, bo, x,
                                           beta, ln1w, ln1b, hb, hbb);

  // FFN
  gemm_awf32<<<gF1, blk, 0, stream>>>(hbb, w1, tmpF2, NROWS, DMODEL, DFF, DMODEL/2);
  ffn1_post<<<NROWS, blk, 0, stream>>>(hb, tmpF2, b1, fbb, fnorm);
  gemm_awf32<<<gF2, blk, 0, stream>>>(fbb, w2, gparts, NROWS, DFF, DMODEL, DFF/4);
  post_resid_ln<<<NROWS, blk, 0, stream>>>(nullptr, fnorm, DFF, gparts, 4, b2, hb,
                                           beta, ln2w, ln2b, out, nullptr);
}

// Round 16
// 111.427 us; speedup vs baseline: 1.1054x; 1.1054x over previous
//
#include <hip/hip_runtime.h>
#include <hip/hip_bf16.h>
#include <math.h>

#define BATCH 2
#define SEQ 196
#define DMODEL 768
#define NHEAD 12
#define DHEAD 64
#define DFF 3072
#define NROWS (BATCH*SEQ)        // 392
#define NBH   (BATCH*NHEAD)     // 24
#define NHROWS (NBH*SEQ)        // 4704

typedef __attribute__((ext_vector_type(8))) short short8;
typedef __attribute__((ext_vector_type(4))) float f32x4;

// ---------- utilities ----------
__device__ __forceinline__ short f2bf(float f) {
  unsigned u = __builtin_bit_cast(unsigned, f);
  u += 0x7FFFu + ((u >> 16) & 1u);      // round-to-nearest-even
  return (short)(u >> 16);
}
__device__ __forceinline__ float bf2f(short s) {
  unsigned u = ((unsigned)(unsigned short)s) << 16;
  return __builtin_bit_cast(float, u);
}
__device__ __forceinline__ float wave_sum64(float v) {
  #pragma unroll
  for (int off = 32; off; off >>= 1) v += __shfl_xor(v, off);
  return v;
}

__device__ __forceinline__ void block_reduce_sum4(float& a, float& b, float& c, float& d,
                                                  float* sbuf /*>=16 floats*/) {
  #pragma unroll
  for (int off = 32; off; off >>= 1) {
    a += __shfl_xor(a, off);
    b += __shfl_xor(b, off);
    c += __shfl_xor(c, off);
    d += __shfl_xor(d, off);
  }
  int wid = threadIdx.x >> 6;
  if ((threadIdx.x & 63) == 0) {
    sbuf[wid*4+0] = a; sbuf[wid*4+1] = b; sbuf[wid*4+2] = c; sbuf[wid*4+3] = d;
  }
  __syncthreads();
  a = sbuf[0] + sbuf[4] + sbuf[8]  + sbuf[12];
  b = sbuf[1] + sbuf[5] + sbuf[9]  + sbuf[13];
  c = sbuf[2] + sbuf[6] + sbuf[10] + sbuf[14];
  d = sbuf[3] + sbuf[7] + sbuf[11] + sbuf[15];
  __syncthreads();
}

#define PITCH 72

// ---------- QKV GEMM: f32 inputs, inline bf16 conversion; z selects wq/wk/wv ----------
__global__ __launch_bounds__(256) void gemm_qkv_f32(
    const float* __restrict__ X,
    const float* __restrict__ Wq, const float* __restrict__ Wk, const float* __restrict__ Wv,
    float* __restrict__ Yq, float* __restrict__ Yk, float* __restrict__ Yv) {
  const float* W = Wq; float* Y = Yq;
  if (blockIdx.z == 1) { W = Wk; Y = Yk; }
  else if (blockIdx.z == 2) { W = Wv; Y = Yv; }
  const int K = DMODEL, m = DMODEL, n = NROWS;

  __shared__ short As[64*PITCH];
  __shared__ short Bs[64*PITCH];
  const int tid  = threadIdx.x;
  const int lane = tid & 63;
  const int w    = tid >> 6, wr = w >> 1, wc = w & 1;
  const int brow = blockIdx.y * 64, bcol = blockIdx.x * 64;

  const int sr = tid >> 2, sc = (tid & 3) * 16;
  const bool rok = (brow + sr) < n;
  const float* xp = X + (size_t)(brow + sr) * K + sc;
  const float* wp = W + (size_t)(bcol + sr) * K + sc;

  f32x4 acc[2][2] = {};
  const int kgo = (lane >> 4) * 8;
  const f32x4 zf = {0.f,0.f,0.f,0.f};

  f32x4 xa[4], wa[4];
  #pragma unroll
  for (int q = 0; q < 4; ++q) {
    xa[q] = rok ? *(const f32x4*)(xp + q*4) : zf;
    wa[q] = *(const f32x4*)(wp + q*4);
  }

  const int T = K / 64;
  for (int t = 0; t < T; ++t) {
    f32x4 xn[4], wn[4];
    const int kn = (t + 1 < T) ? (t + 1) * 64 : 0;
    #pragma unroll
    for (int q = 0; q < 4; ++q) {
      xn[q] = rok ? *(const f32x4*)(xp + kn + q*4) : zf;
      wn[q] = *(const f32x4*)(wp + kn + q*4);
    }

    short8 xs0, xs1, ws0, ws1;
    #pragma unroll
    for (int j = 0; j < 4; ++j) {
      xs0[j] = f2bf(xa[0][j]); xs0[j+4] = f2bf(xa[1][j]);
      xs1[j] = f2bf(xa[2][j]); xs1[j+4] = f2bf(xa[3][j]);
      ws0[j] = f2bf(wa[0][j]); ws0[j+4] = f2bf(wa[1][j]);
      ws1[j] = f2bf(wa[2][j]); ws1[j+4] = f2bf(wa[3][j]);
    }
    __syncthreads();
    *(short8*)&As[sr*PITCH + sc]     = xs0;
    *(short8*)&As[sr*PITCH + sc + 8] = xs1;
    *(short8*)&Bs[sr*PITCH + sc]     = ws0;
    *(short8*)&Bs[sr*PITCH + sc + 8] = ws1;
    __syncthreads();

    #pragma unroll
    for (int kk = 0; kk < 2; ++kk) {
      short8 a0 = *(const short8*)&As[(wr*32      + (lane & 15))*PITCH + kk*32 + kgo];
      short8 a1 = *(const short8*)&As[(wr*32 + 16 + (lane & 15))*PITCH + kk*32 + kgo];
      short8 b0 = *(const short8*)&Bs[(wc*32      + (lane & 15))*PITCH + kk*32 + kgo];
      short8 b1 = *(const short8*)&Bs[(wc*32 + 16 + (lane & 15))*PITCH + kk*32 + kgo];
      acc[0][0] = __builtin_amdgcn_mfma_f32_16x16x32_bf16(a0, b0, acc[0][0], 0, 0, 0);
      acc[0][1] = __builtin_amdgcn_mfma_f32_16x16x32_bf16(a0, b1, acc[0][1], 0, 0, 0);
      acc[1][0] = __builtin_amdgcn_mfma_f32_16x16x32_bf16(a1, b0, acc[1][0], 0, 0, 0);
      acc[1][1] = __builtin_amdgcn_mfma_f32_16x16x32_bf16(a1, b1, acc[1][1], 0, 0, 0);
    }
    #pragma unroll
    for (int q = 0; q < 4; ++q) { xa[q] = xn[q]; wa[q] = wn[q]; }
  }

  const int ccol = bcol + wc*32 + (lane & 15);
  #pragma unroll
  for (int mr = 0; mr < 2; ++mr) {
    #pragma unroll
    for (int j = 0; j < 4; ++j) {
      int grow = brow + wr*32 + mr*16 + (lane >> 4)*4 + j;
      if (grow < n) {
        float* yr = Y + (size_t)grow * m + ccol;
        yr[0]  = acc[mr][0][j];
        yr[16] = acc[mr][1][j];
      }
    }
  }
}

// ---------- GEMM: A bf16, W f32 (inline cvt), split-K via blockIdx.z ----------
// Yparts[z][n][m]; z covers K-range [z*KK, (z+1)*KK)
__global__ __launch_bounds__(256) void gemm_awf32(
    const short* __restrict__ A, const float* __restrict__ W,
    float* __restrict__ Yparts, int n, int Ktot, int m, int KK) {
  const int z = blockIdx.z;
  const int kbase = z * KK;
  float* Y = Yparts + (size_t)z * n * m;

  __shared__ short As[64*PITCH];
  __shared__ short Bs[64*PITCH];
  const int tid  = threadIdx.x;
  const int lane = tid & 63;
  const int w    = tid >> 6, wr = w >> 1, wc = w & 1;
  const int brow = blockIdx.y * 64, bcol = blockIdx.x * 64;

  const int sr = tid >> 2, sc = (tid & 3) * 16;
  const bool rok = (brow + sr) < n;
  const short* ap = A + (size_t)(brow + sr) * Ktot + kbase + sc;
  const float* wp = W + (size_t)(bcol + sr) * Ktot + kbase + sc;

  f32x4 acc[2][2] = {};
  const int kgo = (lane >> 4) * 8;
  const short8 z8 = {0,0,0,0,0,0,0,0};

  short8 aa0, aa1;
  f32x4 wa[4];
  if (rok) { aa0 = *(const short8*)(ap); aa1 = *(const short8*)(ap + 8); }
  else     { aa0 = z8; aa1 = z8; }
  #pragma unroll
  for (int q = 0; q < 4; ++q) wa[q] = *(const f32x4*)(wp + q*4);

  const int T = KK / 64;
  for (int t = 0; t < T; ++t) {
    short8 an0, an1;
    f32x4 wn[4];
    const int kn = (t + 1 < T) ? (t + 1) * 64 : 0;
    if (rok) { an0 = *(const short8*)(ap + kn); an1 = *(const short8*)(ap + kn + 8); }
    else     { an0 = z8; an1 = z8; }
    #pragma unroll
    for (int q = 0; q < 4; ++q) wn[q] = *(const f32x4*)(wp + kn + q*4);

    short8 ws0, ws1;
    #pragma unroll
    for (int j = 0; j < 4; ++j) {
      ws0[j] = f2bf(wa[0][j]); ws0[j+4] = f2bf(wa[1][j]);
      ws1[j] = f2bf(wa[2][j]); ws1[j+4] = f2bf(wa[3][j]);
    }
    __syncthreads();
    *(short8*)&As[sr*PITCH + sc]     = aa0;
    *(short8*)&As[sr*PITCH + sc + 8] = aa1;
    *(short8*)&Bs[sr*PITCH + sc]     = ws0;
    *(short8*)&Bs[sr*PITCH + sc + 8] = ws1;
    __syncthreads();

    #pragma unroll
    for (int kk = 0; kk < 2; ++kk) {
      short8 a0 = *(const short8*)&As[(wr*32      + (lane & 15))*PITCH + kk*32 + kgo];
      short8 a1 = *(const short8*)&As[(wr*32 + 16 + (lane & 15))*PITCH + kk*32 + kgo];
      short8 b0 = *(const short8*)&Bs[(wc*32      + (lane & 15))*PITCH + kk*32 + kgo];
      short8 b1 = *(const short8*)&Bs[(wc*32 + 16 + (lane & 15))*PITCH + kk*32 + kgo];
      acc[0][0] = __builtin_amdgcn_mfma_f32_16x16x32_bf16(a0, b0, acc[0][0], 0, 0, 0);
      acc[0][1] = __builtin_amdgcn_mfma_f32_16x16x32_bf16(a0, b1, acc[0][1], 0, 0, 0);
      acc[1][0] = __builtin_amdgcn_mfma_f32_16x16x32_bf16(a1, b0, acc[1][0], 0, 0, 0);
      acc[1][1] = __builtin_amdgcn_mfma_f32_16x16x32_bf16(a1, b1, acc[1][1], 0, 0, 0);
    }
    aa0 = an0; aa1 = an1;
    #pragma unroll
    for (int q = 0; q < 4; ++q) wa[q] = wn[q];
  }

  const int ccol = bcol + wc*32 + (lane & 15);
  #pragma unroll
  for (int mr = 0; mr < 2; ++mr) {
    #pragma unroll
    for (int j = 0; j < 4; ++j) {
      int grow = brow + wr*32 + mr*16 + (lane >> 4)*4 + j;
      if (grow < n) {
        float* yr = Y + (size_t)grow * m + ccol;
        yr[0]  = acc[mr][0][j];
        yr[16] = acc[mr][1][j];
      }
    }
  }
}

// ---------- fused QKV post (round-7-verified) ----------
#define P_P 256
__global__ __launch_bounds__(256) void qkv_post(const float* __restrict__ X,
                                                const float* __restrict__ MQ,
                                                const float* __restrict__ MK,
                                                const float* __restrict__ MV,
                                                const float* __restrict__ bq,
                                                const float* __restrict__ bk,
                                                const float* __restrict__ bv,
                                                short* __restrict__ qhb,
                                                short* __restrict__ khb,
                                                float* __restrict__ q2s,
                                                float* __restrict__ k2s,
                                                short* __restrict__ lvT) {
  __shared__ float sbuf[16];
  const int r = blockIdx.x;
  const int b = r / SEQ, s = r % SEQ;
  const int y = blockIdx.y;
  const float* MX   = (y == 0) ? MQ : (y == 1) ? MK : MV;
  const float* bias = (y == 0) ? bq : (y == 1) ? bk : bv;
  const float* xr = X + (size_t)r*DMODEL;
  const float* mr = MX + (size_t)r*DMODEL;
  const int tid = threadIdx.x, wid = tid >> 6, lane = tid & 63;
  const float maxn = 1.0f - 1e-5f;

  float xs = 0.f, ms = 0.f, mb = 0.f, bb = 0.f;
  float mv[3], bvv[3];
  #pragma unroll
  for (int l = 0; l < 3; ++l) {
    int i = tid + l*256;
    float xv = xr[i];
    mv[l] = mr[i]; bvv[l] = bias[i];
    xs += xv*xv; ms += mv[l]*mv[l]; mb += mv[l]*bvv[l]; bb += bvv[l]*bvv[l];
  }
  block_reduce_sum4(xs, ms, mb, bb, sbuf);
  float xn  = sqrtf(fmaxf(xs, 1e-15f));
  float mxn = sqrtf(fmaxf(ms, 1e-15f));
  float art = atanhf(fminf(xn, maxn));
  float scm = tanhf(mxn/xn*art)/mxn;
  float x2 = scm*scm*ms;
  float y2 = bb;
  float xy = scm*mb;
  float den = fmaxf(1.f + 2.f*xy + x2*y2, 1e-15f);
  float ca = (1.f + 2.f*xy + y2) * scm / den;
  float cb = (1.f - x2) / den;

  #pragma unroll
  for (int l = 0; l < 3; ++l) {
    float o = ca*mv[l] + cb*bvv[l];
    int h = l*4 + wid;
    size_t hr = (size_t)(b*NHEAD + h)*SEQ + s;
    if (y < 2) {
      short c16 = f2bf(fminf(o, maxn));
      float cf = bf2f(c16);
      float nn = wave_sum64(cf*cf);
      if (y == 0) {
        qhb[hr*64 + lane] = c16;
        if (lane == 0) q2s[hr] = nn;
      } else {
        khb[hr*64 + lane] = c16;
        if (lane == 0) k2s[hr] = nn;
      }
    } else {
      float nn = wave_sum64(o*o);
      float n = sqrtf(fmaxf(nn, 1e-15f));
      float scl = atanhf(fminf(n, maxn))/n;
      lvT[((size_t)(b*NHEAD + h)*DHEAD + lane)*P_P + s] = f2bf(scl*o);
    }
  }
}

// ---------- fully fused attention: S=QK^T -> dist+softmax -> PV -> expmap0 ----------
#define SP 72
#define PP 264
__global__ __launch_bounds__(256) void attn_mfma(
    const short* __restrict__ qhb, const short* __restrict__ khb,
    const float* __restrict__ q2s, const float* __restrict__ k2s,
    const short* __restrict__ lvT, const float* __restrict__ hs,
    short* __restrict__ aob) {
  __shared__ __align__(16) char smem[9216 + 224*SP*2];
  __shared__ float q2l[64];
  __shared__ float k2l[224];
  __shared__ float redA[64][2];
  __shared__ float redB[64][2];

  const int tile = blockIdx.x, bh = blockIdx.z;
  const int h = bh % NHEAD, b = bh / NHEAD;
  const int i0 = tile*64;
  const int tid = threadIdx.x, lane = tid & 63, w = tid >> 6, wr = w >> 1, wc = w & 1;
  short* Qs = (short*)smem;
  short* Ks = (short*)(smem + 9216);
  short* Pl = (short*)smem;
  const short8 z8 = {0,0,0,0,0,0,0,0};
  const int kgo = (lane >> 4)*8;

  {
    int row = tid >> 2, seg = (tid & 3)*16;
    int gr = i0 + row;
    short8 v0 = z8, v1 = z8;
    if (gr < SEQ) {
      const short* p = qhb + ((size_t)bh*SEQ + gr)*64 + seg;
      v0 = *(const short8*)p; v1 = *(const short8*)(p + 8);
    }
    *(short8*)&Qs[row*SP + seg]     = v0;
    *(short8*)&Qs[row*SP + seg + 8] = v1;
  }
  for (int u = tid; u < 224*4; u += 256) {
    int row = u >> 2, seg = (u & 3)*16;
    short8 v0 = z8, v1 = z8;
    if (row < SEQ) {
      const short* p = khb + ((size_t)bh*SEQ + row)*64 + seg;
      v0 = *(const short8*)p; v1 = *(const short8*)(p + 8);
    }
    *(short8*)&Ks[row*SP + seg]     = v0;
    *(short8*)&Ks[row*SP + seg + 8] = v1;
  }
  if (tid < 64)  q2l[tid] = (i0 + tid < SEQ) ? q2s[(size_t)bh*SEQ + i0 + tid] : 0.f;
  if (tid < 224) k2l[tid] = (tid < SEQ) ? k2s[(size_t)bh*SEQ + tid] : 0.f;
  __syncthreads();

  f32x4 acc[2][7] = {};
  #pragma unroll
  for (int kk = 0; kk < 2; ++kk) {
    short8 a0 = *(const short8*)&Qs[(wr*32      + (lane & 15))*SP + kk*32 + kgo];
    short8 a1 = *(const short8*)&Qs[(wr*32 + 16 + (lane & 15))*SP + kk*32 + kgo];
    #pragma unroll
    for (int cf = 0; cf < 7; ++cf) {
      short8 bf = *(const short8*)&Ks[(wc*112 + cf*16 + (lane & 15))*SP + kk*32 + kgo];
      acc[0][cf] = __builtin_amdgcn_mfma_f32_16x16x32_bf16(a0, bf, acc[0][cf], 0, 0, 0);
      acc[1][cf] = __builtin_amdgcn_mfma_f32_16x16x32_bf16(a1, bf, acc[1][cf], 0, 0, 0);
    }
  }

  const float inv_hsv = 1.f/(hs[h]*8.0f);
  #pragma unroll
  for (int rf = 0; rf < 2; ++rf) {
    #pragma unroll
    for (int j = 0; j < 4; ++j) {
      int rl = wr*32 + rf*16 + (lane >> 4)*4 + j;
      float q2 = q2l[rl];
      #pragma unroll
      for (int cf = 0; cf < 7; ++cf) {
        int col = wc*112 + cf*16 + (lane & 15);
        float kq = acc[rf][cf][j];
        float k2 = k2l[col];
        float xy = -kq;
        float al = 1.f + 2.f*xy + q2;
        float be = 1.f - k2;
        float num2 = al*al*k2 + 2.f*al*be*xy + be*be*q2;
        float den  = fmaxf(1.f + 2.f*xy + k2*q2, 1e-15f);
        float dns  = num2/(den*den);
        float denom = (1.f - q2)*(1.f - k2) + 1e-15f;
        float arg = fmaxf(1.f + 2.f*dns/denom, 1.f + 1e-7f);
        float dist = logf(arg + sqrtf(arg*arg - 1.f));
        acc[rf][cf][j] = (col < SEQ) ? -dist*inv_hsv : -1e30f;
      }
      float m = acc[rf][0][j];
      #pragma unroll
      for (int cf = 1; cf < 7; ++cf) m = fmaxf(m, acc[rf][cf][j]);
      m = fmaxf(m, __shfl_xor(m, 1));
      m = fmaxf(m, __shfl_xor(m, 2));
      m = fmaxf(m, __shfl_xor(m, 4));
      m = fmaxf(m, __shfl_xor(m, 8));
      if ((lane & 15) == 0) redA[rl][wc] = m;
    }
  }
  __syncthreads();

  #pragma unroll
  for (int rf = 0; rf < 2; ++rf) {
    #pragma unroll
    for (int j = 0; j < 4; ++j) {
      int rl = wr*32 + rf*16 + (lane >> 4)*4 + j;
      float m = fmaxf(redA[rl][0], redA[rl][1]);
      float s = 0.f;
      #pragma unroll
      for (int cf = 0; cf < 7; ++cf) {
        float e = expf(acc[rf][cf][j] - m);
        acc[rf][cf][j] = e;
        s += e;
      }
      s += __shfl_xor(s, 1); s += __shfl_xor(s, 2);
      s += __shfl_xor(s, 4); s += __shfl_xor(s, 8);
      if ((lane & 15) == 0) redB[rl][wc] = s;
    }
  }
  __syncthreads();

  #pragma unroll
  for (int rf = 0; rf < 2; ++rf) {
    #pragma unroll
    for (int j = 0; j < 4; ++j) {
      int rl = wr*32 + rf*16 + (lane >> 4)*4 + j;
      float inv = 1.f/(redB[rl][0] + redB[rl][1]);
      #pragma unroll
      for (int cf = 0; cf < 7; ++cf) {
        int col = wc*112 + cf*16 + (lane & 15);
        Pl[rl*PP + col] = f2bf(acc[rf][cf][j]*inv);
      }
    }
  }
  __syncthreads();

  f32x4 acc2[2][2] = {};
  const short* lvb = lvT + (size_t)bh*DHEAD*P_P;
  #pragma unroll
  for (int ks = 0; ks < 7; ++ks) {
    short8 a0 = *(const short8*)&Pl[(wr*32      + (lane & 15))*PP + ks*32 + kgo];
    short8 a1 = *(const short8*)&Pl[(wr*32 + 16 + (lane & 15))*PP + ks*32 + kgo];
    short8 b0 = *(const short8*)(lvb + (size_t)(wc*32      + (lane & 15))*P_P + ks*32 + kgo);
    short8 b1 = *(const short8*)(lvb + (size_t)(wc*32 + 16 + (lane & 15))*P_P + ks*32 + kgo);
    acc2[0][0] = __builtin_amdgcn_mfma_f32_16x16x32_bf16(a0, b0, acc2[0][0], 0, 0, 0);
    acc2[0][1] = __builtin_amdgcn_mfma_f32_16x16x32_bf16(a0, b1, acc2[0][1], 0, 0, 0);
    acc2[1][0] = __builtin_amdgcn_mfma_f32_16x16x32_bf16(a1, b0, acc2[1][0], 0, 0, 0);
    acc2[1][1] = __builtin_amdgcn_mfma_f32_16x16x32_bf16(a1, b1, acc2[1][1], 0, 0, 0);
  }

  #pragma unroll
  for (int rf = 0; rf < 2; ++rf) {
    #pragma unroll
    for (int j = 0; j < 4; ++j) {
      int rl = wr*32 + rf*16 + (lane >> 4)*4 + j;
      float s = acc2[rf][0][j]*acc2[rf][0][j] + acc2[rf][1][j]*acc2[rf][1][j];
      s += __shfl_xor(s, 1); s += __shfl_xor(s, 2);
      s += __shfl_xor(s, 4); s += __shfl_xor(s, 8);
      if ((lane & 15) == 0) redA[rl][wc] = s;
    }
  }
  __syncthreads();

  #pragma unroll
  for (int rf = 0; rf < 2; ++rf) {
    #pragma unroll
    for (int j = 0; j < 4; ++j) {
      int rl = wr*32 + rf*16 + (lane >> 4)*4 + j;
      int grow = i0 + rl;
      if (grow < SEQ) {
        float n2 = redA[rl][0] + redA[rl][1];
        float n = sqrtf(fmaxf(n2, 1e-15f));
        float scl = tanhf(n)/n;
        #pragma unroll
        for (int cf2 = 0; cf2 < 2; ++cf2) {
          int col = h*64 + wc*32 + cf2*16 + (lane & 15);
          float o = scl*acc2[rf][cf2][j];
          aob[(size_t)(b*SEQ + grow)*DMODEL + col] = f2bf(o);
        }
      }
    }
  }
}

// ---------- fused hyp_linear epilogue + residual + hyp layer norm (split-K partial sum) ----------
// Xbf!=null: xs = ||bf16 Xbf row||^2 (din wide); else xs = xsArr[r].
__global__ __launch_bounds__(256) void post_resid_ln(
    const short* __restrict__ Xbf, const float* __restrict__ xsArr, int din,
    const float* __restrict__ MXp, int nparts,
    const float* __restrict__ bias, const float* __restrict__ RX,
    const float* __restrict__ betap, const float* __restrict__ lnw,
    const float* __restrict__ lnb,
    float* __restrict__ out, short* __restrict__ outb) {
  __shared__ float sbuf[16];
  const int r = blockIdx.x;
  const int tid = threadIdx.x;

  float xs = 0.f, ms = 0.f, mb = 0.f, bb = 0.f;
  float mv[3], bvv[3];
  #pragma unroll
  for (int l = 0; l < 3; ++l) {
    int i = tid + l*256;
    float acc = 0.f;
    for (int p = 0; p < nparts; ++p)
      acc += MXp[(size_t)p*NROWS*DMODEL + (size_t)r*DMODEL + i];
    mv[l] = acc; bvv[l] = bias[i];
    ms += mv[l]*mv[l]; mb += mv[l]*bvv[l]; bb += bvv[l]*bvv[l];
  }
  if (Xbf) {
    const short* xr = Xbf + (size_t)r*din;
    for (int i = tid; i < din; i += 256) { float v = bf2f(xr[i]); xs += v*v; }
  }
  block_reduce_sum4(xs, ms, mb, bb, sbuf);
  if (!Xbf) xs = xsArr[r];

  float xn  = sqrtf(fmaxf(xs, 1e-15f));
  float mxn = sqrtf(fmaxf(ms, 1e-15f));
  float art = atanhf(fminf(xn, 1.f - 1e-5f));
  float scm = tanhf(mxn/xn*art)/mxn;
  float px2 = scm*scm*ms;
  float py2 = bb;
  float pxy = scm*mb;
  float pden = fmaxf(1.f + 2.f*pxy + px2*py2, 1e-15f);
  float pca = (1.f + 2.f*pxy + py2) * scm / pden;
  float pcb = (1.f - px2) / pden;

  const float* xr2 = RX + (size_t)r*DMODEL;
  float xv[3], yv[3];
  float x2 = 0.f, xy = 0.f, d1 = 0.f, d2 = 0.f;
  #pragma unroll
  for (int l = 0; l < 3; ++l) {
    int i = tid + l*256;
    xv[l] = xr2[i];
    yv[l] = pca*mv[l] + pcb*bvv[l];
    x2 += xv[l]*xv[l]; xy += xv[l]*yv[l];
  }
  block_reduce_sum4(x2, xy, d1, d2, sbuf);
  float yy = pca*pca*ms + 2.f*pca*pcb*mb + pcb*pcb*bb;

  float beta = betap[0];
  float ny = sqrtf(fmaxf(yy, 1e-15f));
  float scs = tanhf(beta * atanhf(fminf(ny, 1.f - 1e-5f))) / ny;
  float y2  = scs*scs*yy;
  float xys = scs*xy;
  float den = fmaxf(1.f + 2.f*xys + x2*y2, 1e-15f);
  float ca = (1.f + 2.f*xys + y2)/den;
  float cb = (1.f - x2)*scs/den;
  float hv[3]; float h2 = 0.f;
  #pragma unroll
  for (int l = 0; l < 3; ++l) { hv[l] = ca*xv[l] + cb*yv[l]; h2 += hv[l]*hv[l]; }
  float z1 = 0.f, z2 = 0.f, z3 = 0.f;
  block_reduce_sum4(h2, z1, z2, z3, sbuf);

  float nh = sqrtf(fmaxf(h2, 1e-15f));
  float scl = atanhf(fminf(nh, 1.f - 1e-5f))/nh;
  float tv[3]; float tsum = 0.f, tsq = 0.f;
  #pragma unroll
  for (int l = 0; l < 3; ++l) { tv[l] = scl*hv[l]; tsum += tv[l]; tsq += tv[l]*tv[l]; }
  float zz = 0.f, zw = 0.f;
  block_reduce_sum4(tsum, tsq, zz, zw, sbuf);
  float mu  = tsum * (1.f/768.f);
  float var = tsq * (1.f/768.f) - mu*mu;
  float rstd = rsqrtf(var + 1e-5f);
  float lnv[3]; float l2 = 0.f;
  #pragma unroll
  for (int l = 0; l < 3; ++l) {
    int i = tid + l*256;
    lnv[l] = (tv[l] - mu)*rstd*lnw[i] + lnb[i];
    l2 += lnv[l]*lnv[l];
  }
  float w1 = 0.f, w2 = 0.f, w3 = 0.f;
  block_reduce_sum4(l2, w1, w2, w3, sbuf);
  float nl = sqrtf(fmaxf(l2, 1e-15f));
  float sce = tanhf(nl)/nl;
  #pragma unroll
  for (int l = 0; l < 3; ++l) {
    int i = tid + l*256;
    float o = sce*lnv[l];
    out[(size_t)r*DMODEL + i] = o;
    if (outb) outb[(size_t)r*DMODEL + i] = f2bf(o);
  }
}

// ---------- fused FFN1 epilogue: hyp_linear post + mobius_relu -> bf16 + row norm ----------
__global__ __launch_bounds__(256) void ffn1_post(const float* __restrict__ hb,
                                                 const float* __restrict__ MX,
                                                 const float* __restrict__ bias,
                                                 short* __restrict__ fbb,
                                                 float* __restrict__ fnorm) {
  __shared__ float sbuf[16];
  const int r = blockIdx.x;
  const int tid = threadIdx.x;
  const float* xr = hb + (size_t)r*DMODEL;
  const float* mr = MX + (size_t)r*DFF;

  float xs = 0.f, ms = 0.f, mb = 0.f, bb = 0.f;
  float mv[12], bvv[12];
  for (int i = tid; i < DMODEL; i += 256) { float v = xr[i]; xs += v*v; }
  #pragma unroll
  for (int l = 0; l < 12; ++l) {
    int i = tid + l*256;
    mv[l] = mr[i]; bvv[l] = bias[i];
    ms += mv[l]*mv[l]; mb += mv[l]*bvv[l]; bb += bvv[l]*bvv[l];
  }
  block_reduce_sum4(xs, ms, mb, bb, sbuf);
  float xn  = sqrtf(fmaxf(xs, 1e-15f));
  float mxn = sqrtf(fmaxf(ms, 1e-15f));
  float art = atanhf(fminf(xn, 1.f - 1e-5f));
  float scm = tanhf(mxn/xn*art)/mxn;
  float px2 = scm*scm*ms;
  float py2 = bb;
  float pxy = scm*mb;
  float pden = fmaxf(1.f + 2.f*pxy + px2*py2, 1e-15f);
  float pca = (1.f + 2.f*pxy + py2) * scm / pden;
  float pcb = (1.f - px2) / pden;

  float s2 = pca*pca*ms + 2.f*pca*pcb*mb + pcb*pcb*bb;
  float n = sqrtf(fmaxf(s2, 1e-15f));
  float scl = atanhf(fminf(n, 1.f - 1e-5f))/n;
  float rv[12]; float r2 = 0.f;
  #pragma unroll
  for (int l = 0; l < 12; ++l) {
    float f = pca*mv[l] + pcb*bvv[l];
    rv[l] = fmaxf(scl*f, 0.f);
    r2 += rv[l]*rv[l];
  }
  float w1 = 0.f, w2 = 0.f, w3 = 0.f;
  block_reduce_sum4(r2, w1, w2, w3, sbuf);
  float nr = sqrtf(fmaxf(r2, 1e-15f));
  float sce = tanhf(nr)/nr;
  #pragma unroll
  for (int l = 0; l < 12; ++l)
    fbb[(size_t)r*DFF + tid + l*256] = f2bf(sce*rv[l]);
  if (tid == 0) fnorm[r] = sce*sce*r2;
}

extern "C" void kernel_launch(void* const* d_in, const int* in_sizes, int n_in,
                              void* d_out, int out_size, void* d_ws, size_t ws_size,
                              hipStream_t stream) {
  const float* x    = (const float*)d_in[0];
  const float* wq   = (const float*)d_in[1];
  const float* bq   = (const float*)d_in[2];
  const float* wk   = (const float*)d_in[3];
  const float* bk   = (const float*)d_in[4];
  const float* wv   = (const float*)d_in[5];
  const float* bv   = (const float*)d_in[6];
  const float* wo   = (const float*)d_in[7];
  const float* bo   = (const float*)d_in[8];
  const float* hs   = (const float*)d_in[9];
  const float* w1   = (const float*)d_in[10];
  const float* b1   = (const float*)d_in[11];
  const float* w2   = (const float*)d_in[12];
  const float* b2   = (const float*)d_in[13];
  const float* beta = (const float*)d_in[14];
  const float* ln1w = (const float*)d_in[15];
  const float* ln1b = (const float*)d_in[16];
  const float* ln2w = (const float*)d_in[17];
  const float* ln2b = (const float*)d_in[18];
  float* out = (float*)d_out;

  char* base = (char*)d_ws;
  size_t off = 0;
  auto allocB = [&](size_t bytes) {
    off = (off + 63) & ~(size_t)63;
    void* p = base + off; off += bytes; return p;
  };
  short* aob  = (short*)allocB((size_t)NROWS*DMODEL * 2);
  short* hbb  = (short*)allocB((size_t)NROWS*DMODEL * 2);
  short* fbb  = (short*)allocB((size_t)NROWS*DFF * 2);
  float* tq   = (float*)allocB((size_t)NROWS*DMODEL * 4);
  float* tk   = (float*)allocB((size_t)NROWS*DMODEL * 4);
  float* tv   = (float*)allocB((size_t)NROWS*DMODEL * 4);
  float* gparts = (float*)allocB((size_t)4*NROWS*DMODEL * 4);   // split-K partials
  short* qhb  = (short*)allocB((size_t)NHROWS*DHEAD * 2);
  short* khb  = (short*)allocB((size_t)NHROWS*DHEAD * 2);
  float* q2s  = (float*)allocB((size_t)NHROWS * 4);
  float* k2s  = (float*)allocB((size_t)NHROWS * 4);
  short* lvT  = (short*)allocB((size_t)NBH*DHEAD*P_P * 2);
  float* hb   = (float*)allocB((size_t)NROWS*DMODEL * 4);
  float* tmpF = (float*)allocB((size_t)NROWS*DFF * 4);
  float* fnorm= (float*)allocB((size_t)NROWS * 4);

  dim3 blk(256);
  dim3 gQKV(DMODEL/64, (NROWS+63)/64, 3);   // 252 blocks
  dim3 gO(DMODEL/64,   (NROWS+63)/64, 2);   // split-K=2, 168 blocks
  dim3 gF1(DFF/64,     (NROWS+63)/64, 1);   // 336 blocks
  dim3 gF2(DMODEL/64,  (NROWS+63)/64, 4);   // split-K=4, 336 blocks
  dim3 gATT(4, 1, NBH);                     // 96 blocks

  // QKV projections (inline f32->bf16) + fused post
  gemm_qkv_f32<<<gQKV, blk, 0, stream>>>(x, wq, wk, wv, tq, tk, tv);
  qkv_post<<<dim3(NROWS, 3), blk, 0, stream>>>(x, tq, tk, tv, bq, bk, bv,
                                               qhb, khb, q2s, k2s, lvT);

  // fused attention
  attn_mfma<<<gATT, blk, 0, stream>>>(qhb, khb, q2s, k2s, lvT, hs, aob);

  // output projection (split-K=2) + fused post/residual/LN1
  gemm_awf32<<<gO, blk, 0, stream>>>(aob, wo, gparts, NROWS, DMODEL, DMODEL, DMODEL/2);
  post_resid_ln<<<NROWS, blk, 0, stream>>>(aob, nullptr, DMODEL, gparts, 2, bo, x,
                                           beta, ln1w, ln1b, hb, hbb);

  // FFN
  gemm_awf32<<<gF1, blk, 0, stream>>>(hbb, w1, tmpF, NROWS, DMODEL, DFF, DMODEL);
  ffn1_post<<<NROWS, blk, 0, stream>>>(hb, tmpF, b1, fbb, fnorm);
  gemm_awf32<<<gF2, blk, 0, stream>>>(fbb, w2, gparts, NROWS, DFF, DMODEL, DFF/4);
  post_resid_ln<<<NROWS, blk, 0, stream>>>(nullptr, fnorm, DFF, gparts, 4, b2, hb,
                                           beta, ln2w, ln2b, out, nullptr);
}